// Round 11
// baseline (191.299 us; speedup 1.0000x reference)
//
#include <hip/hip_runtime.h>
#include <math.h>

#define N_TOT 8192
#define N_SRC 4096
#define D_DIM 512
#define BM2 256
#define NT2 (N_TOT / BM2)             /* 32 tiles per dim */
#define NTILES2 (NT2 * (NT2 + 1) / 2) /* 528; 528 % 8 == 0 */
#define NPREP 256

typedef short bf16x8 __attribute__((ext_vector_type(8)));
typedef unsigned short u16x8 __attribute__((ext_vector_type(8)));
typedef float f32x4 __attribute__((ext_vector_type(4)));

// ws layout (bytes):
//   0      : double accum[4]   {2=loss}
//   64     : unsigned int cnt
//   128    : float invbw[5]
//   4096   : float sq[8192]          (32 KB)
//   36864  : float w[4096]           (16 KB)
//   53248  : float colpart[256][512] (512 KB)
//   577536 : ushort xhi[8192*512]    (8 MB)

__device__ __forceinline__ unsigned short f2bf_rn(float v) {
    unsigned int u = __float_as_uint(v);
    unsigned int r = (u + 0x7FFFu + ((u >> 16) & 1u)) >> 16;
    return (unsigned short)r;
}

// One pass over x: bf16 round + row sum-of-squares + column-sum partial slots.
__global__ __launch_bounds__(256) void k_prep(const float* __restrict__ x,
                                              unsigned short* __restrict__ xhi,
                                              float* __restrict__ sq,
                                              float* __restrict__ colpart) {
    const int wave = threadIdx.x >> 6;
    const int lane = threadIdx.x & 63;
    __shared__ float colbuf[4][512];
    float fcol[8];
#pragma unroll
    for (int j = 0; j < 8; ++j) fcol[j] = 0.f;
#pragma unroll
    for (int r8 = 0; r8 < 8; ++r8) {
        const int row = blockIdx.x * 32 + wave * 8 + r8;
        const size_t base = (size_t)row * D_DIM + lane * 8;
        float v[8];
        *(float4*)&v[0] = *(const float4*)(x + base);
        *(float4*)&v[4] = *(const float4*)(x + base + 4);
        u16x8 h;
        float s = 0.f;
#pragma unroll
        for (int j = 0; j < 8; ++j) {
            h[j] = f2bf_rn(v[j]);
            s = fmaf(v[j], v[j], s);
            fcol[j] += v[j];
        }
        *(u16x8*)(xhi + base) = h;
#pragma unroll
        for (int off = 32; off; off >>= 1) s += __shfl_xor(s, off);
        if (lane == 0) sq[row] = s;
    }
#pragma unroll
    for (int j = 0; j < 8; ++j) colbuf[wave][lane * 8 + j] = fcol[j];
    __syncthreads();
    const int c = threadIdx.x * 2;
    float2 r;
    r.x = colbuf[0][c] + colbuf[1][c] + colbuf[2][c] + colbuf[3][c];
    r.y = colbuf[0][c + 1] + colbuf[1][c + 1] + colbuf[2][c + 1] + colbuf[3][c + 1];
    *(float2*)(colpart + (size_t)blockIdx.x * D_DIM + c) = r;
}

// Bandwidth from analytic sum; also weights + zeroing of loss accumulator.
__global__ __launch_bounds__(256) void k_bw(const float* __restrict__ sq,
                                            const float* __restrict__ colpart,
                                            const float* __restrict__ imw,
                                            const int* __restrict__ y,
                                            const int* __restrict__ alpha_p,
                                            float* __restrict__ w,
                                            float* __restrict__ invbw,
                                            double* __restrict__ accum,
                                            unsigned int* __restrict__ cnt) {
    const int tid = threadIdx.x;
    if (tid == 0) { accum[2] = 0.0; *cnt = 0u; }
    const float a = (float)alpha_p[0];
    for (int i = tid; i < N_SRC; i += 256) w[i] = a * imw[y[i]] + (1.0f - a);
    double s2 = 0.0;
    for (int i = tid; i < N_TOT; i += 256) s2 += (double)sq[i];
    double cs0 = 0.0, cs1 = 0.0;
    const int c = tid * 2;
#pragma unroll 8
    for (int b = 0; b < NPREP; ++b) {
        float2 v = *(const float2*)(colpart + (size_t)b * D_DIM + c);
        cs0 += (double)v.x;
        cs1 += (double)v.y;
    }
    double sc = cs0 * cs0 + cs1 * cs1;
    __shared__ double r1[256], r2[256];
    r1[tid] = s2; r2[tid] = sc;
    __syncthreads();
    for (int off = 128; off; off >>= 1) {
        if (tid < off) { r1[tid] += r1[tid + off]; r2[tid] += r2[tid + off]; }
        __syncthreads();
    }
    if (tid == 0) {
        // sum of clamped l2 == analytic sum (clamp only trims diagonal fp noise)
        double sum_l2 = 2.0 * (double)N_TOT * r1[0] - 2.0 * r2[0];
        double bw = sum_l2 / ((double)N_TOT * (double)N_TOT - (double)N_TOT);
        bw *= 0.25;  // / KERNEL_MUL^(KERNEL_NUM/2)
        double m = 1.0;
        for (int i = 0; i < 5; ++i) { invbw[i] = (float)(1.0 / (bw * m)); m *= 2.0; }
    }
}

__device__ __forceinline__ void gload_lds16(const unsigned short* g, char* l) {
    __builtin_amdgcn_global_load_lds((const __attribute__((address_space(1))) void*)g,
                                     (__attribute__((address_space(3))) void*)l,
                                     16, 0, 0);
}

// 256x256 8-phase Gram kernel. R10 geometry/schedule frozen.
// SYNC CHANGE (the experiment): no "memory" clobbers anywhere. Clobbered asm
// is "may read all memory" -> backend must s_waitcnt vmcnt(0) before it
// (pending global_load_lds writes LDS) -> full drain at every barrier, which
// made R5-R10 equivalent. m201's verified idiom: __builtin_amdgcn_s_barrier()
// + bare counted-waitcnt asm + sched_barrier(0) pin. Volatile asm and the
// barrier builtin still fence *memory-op* scheduling at MIR level.
__global__ __launch_bounds__(512, 2) void k_pairs(const unsigned short* __restrict__ xhi,
                                                  const float* __restrict__ sq,
                                                  const float* __restrict__ w,
                                                  const float* __restrict__ invbw,
                                                  double* __restrict__ accum,
                                                  unsigned int* __restrict__ cnt,
                                                  float* __restrict__ out) {
    int bid = (blockIdx.x & 7) * (NTILES2 / 8) + (blockIdx.x >> 3);
    int ti = 0, rem = bid;
    while (rem >= NT2 - ti) { rem -= NT2 - ti; ++ti; }
    const int tj = ti + rem;
    const int i0 = ti * BM2, j0 = tj * BM2;

    __shared__ __align__(16) char lds[2 * 65536];
    __shared__ double sdl8[8];

    const int tid = threadIdx.x;
    const int lane = tid & 63;
    const int wave = tid >> 6;
    const int wr = wave >> 2, wc = wave & 3;   // 2x4 waves; wave owns 128x64
    const int lr = lane & 15, lg = lane >> 4;

    const int aBase = wr * 16384 + lr * 128;
    const int bBase = 32768 + (wc >> 1) * 16384 + (wc & 1) * 8192 + lr * 128;
    int cxor16[2];
    cxor16[0] = ((lg ^ (lr & 7)) << 4);
    cxor16[1] = (((4 + lg) ^ (lr & 7)) << 4);

    const int srow = tid >> 3;
    const int sc = (tid & 7) ^ (srow & 7);  // logical chunk (inverse swizzle)
    const unsigned short* aPanel = xhi + (size_t)i0 * D_DIM;
    const unsigned short* bPanel = xhi + (size_t)j0 * D_DIM;

    f32x4 acc[8][4];
#pragma unroll
    for (int m = 0; m < 8; ++m)
#pragma unroll
        for (int n = 0; n < 4; ++n) acc[m][n] = f32x4{0.f, 0.f, 0.f, 0.f};

#define STAGE_HT(P, h, b, kt)                                                          \
    do {                                                                               \
        const unsigned short* _p = (P) ? bPanel : aPanel;                              \
        char* _dst = lds + (b) * 65536 + (P) * 32768 + (h) * 16384 + tid * 16;         \
        _Pragma("unroll") for (int _r = 0; _r < 2; ++_r) {                             \
            gload_lds16(_p + (size_t)((h) * 128 + _r * 64 + srow) * D_DIM +            \
                            (kt) * 64 + sc * 8,                                        \
                        _dst + _r * 8192);                                             \
        }                                                                              \
    } while (0)

#define WAITV4() do { asm volatile("s_waitcnt vmcnt(4)"); __builtin_amdgcn_sched_barrier(0); } while (0)
#define WAITV0() do { asm volatile("s_waitcnt vmcnt(0)"); __builtin_amdgcn_sched_barrier(0); } while (0)
#define BAR() __builtin_amdgcn_s_barrier()

    // prologue: tile0 {A0,B0,B1,A1}, tile1 {B0,A0}; wait tile0 (leave 4 in flight)
    STAGE_HT(0, 0, 0, 0); STAGE_HT(1, 0, 0, 0); STAGE_HT(1, 1, 0, 0); STAGE_HT(0, 1, 0, 0);
    STAGE_HT(1, 0, 1, 1); STAGE_HT(0, 0, 1, 1);
    WAITV4();
    BAR();

    bf16x8 aR[4][2], bLo[2][2], bHi[2][2];

#define LD_A(Mq)                                                                       \
    _Pragma("unroll") for (int _m = 0; _m < 4; ++_m)                                   \
    _Pragma("unroll") for (int _k = 0; _k < 2; ++_k)                                   \
        aR[_m][_k] = *(const bf16x8*)(base + aBase + (Mq) * 8192 + _m * 2048 + cxor16[_k]);
#define LD_B(dstB, Nq)                                                                 \
    _Pragma("unroll") for (int _n = 0; _n < 2; ++_n)                                   \
    _Pragma("unroll") for (int _k = 0; _k < 2; ++_k)                                   \
        dstB[_n][_k] = *(const bf16x8*)(base + bBase + ((Nq) * 2 + _n) * 2048 + cxor16[_k]);
#define MFMA_Q(Mq, Nq, B)                                                              \
    __builtin_amdgcn_s_setprio(1);                                                     \
    _Pragma("unroll") for (int _m = 0; _m < 4; ++_m)                                   \
    _Pragma("unroll") for (int _n = 0; _n < 2; ++_n)                                   \
    _Pragma("unroll") for (int _k = 0; _k < 2; ++_k)                                   \
        acc[(Mq) * 4 + _m][(Nq) * 2 + _n] = __builtin_amdgcn_mfma_f32_16x16x32_bf16(   \
            aR[_m][_k], B[_n][_k], acc[(Mq) * 4 + _m][(Nq) * 2 + _n], 0, 0, 0);        \
    __builtin_amdgcn_s_setprio(0);

    for (int t = 0; t < 8; ++t) {
        const char* base = lds + (t & 1) * 65536;
        const int bn = (t + 1) & 1;
        // ph0: stage B1(t+1); read A-Mlo + B-Nlo
        if (t < 7) STAGE_HT(1, 1, bn, t + 1);
        LD_A(0); LD_B(bLo, 0);
        BAR(); MFMA_Q(0, 0, bLo); BAR();
        // ph1: stage A1(t+1); read B-Nhi
        if (t < 7) STAGE_HT(0, 1, bn, t + 1);
        LD_B(bHi, 1);
        BAR(); MFMA_Q(0, 1, bHi); BAR();
        // ph2: stage B0(t+2); read A-Mhi
        if (t < 6) STAGE_HT(1, 0, t & 1, t + 2);
        LD_A(1);
        BAR(); MFMA_Q(1, 1, bHi); BAR();
        // ph3: stage A0(t+2); no ds_read (bLo kept); boundary counted vmcnt
        if (t < 6) STAGE_HT(0, 0, t & 1, t + 2);
        BAR(); MFMA_Q(1, 0, bLo);
        if (t < 6) { WAITV4(); }
        else if (t == 6) { WAITV0(); }
        BAR();
    }
#undef STAGE_HT
#undef LD_A
#undef LD_B
#undef MFMA_Q
#undef WAITV4
#undef WAITV0
#undef BAR

    // ---- epilogue ----
    const float nib4 = -invbw[4];
    const bool diag = (ti == tj);
    const int region = (tj < NT2 / 2) ? 0 : ((ti >= NT2 / 2) ? 1 : 2);  // ss/tt/st

    float sqj[4], wj[4];
#pragma unroll
    for (int n = 0; n < 4; ++n) {
        int jg = j0 + wc * 64 + n * 16 + lr;
        sqj[n] = sq[jg];
        wj[n] = (jg < N_SRC) ? w[jg] : 0.f;
    }
    float facc = 0.f;
#pragma unroll
    for (int m = 0; m < 8; ++m)
#pragma unroll
        for (int jj = 0; jj < 4; ++jj) {
            const int rg = wr * 128 + m * 16 + lg * 4 + jj;
            const int i = i0 + rg;
            const float sqi = sq[i];
            const float wi = (i < N_SRC) ? w[i] : 0.f;
#pragma unroll
            for (int n = 0; n < 4; ++n) {
                const int cg = wc * 64 + n * 16 + lr;
                if (diag && rg >= cg) continue;
                float l2 = fmaf(-2.f, acc[m][n][jj], sqi + sqj[n]);
                l2 = fmaxf(l2, 0.f);
                float tt = __expf(l2 * nib4);
                float t2 = tt * tt, t4 = t2 * t2, t8 = t4 * t4, t16 = t8 * t8;
                float k5 = tt + t2 + t4 + t8 + t16;
                float cf;
                if (region == 0)      cf = wi * wj[n];
                else if (region == 1) cf = 1.f;
                else                  cf = wi;
                facc = fmaf(k5, cf, facc);
            }
        }

#pragma unroll
    for (int off = 32; off; off >>= 1) facc += __shfl_xor(facc, off);
    if (lane == 0) sdl8[wave] = (double)facc;
    __syncthreads();
    if (tid == 0) {
        const double C_SS = 1.0 / 8386560.0;
        const double C_ST = 2.0 / 16777216.0;
        double s = 0.0;
#pragma unroll
        for (int q = 0; q < 8; ++q) s += sdl8[q];
        double scale = (region == 2) ? -C_ST : C_SS;
        atomicAdd(&accum[2], scale * s);
        __threadfence();
        unsigned int old = atomicAdd(cnt, 1u);
        if (old == NTILES2 - 1) {
            double v = atomicAdd(&accum[2], 0.0);
            out[0] = (float)v;
        }
    }
}

extern "C" void kernel_launch(void* const* d_in, const int* in_sizes, int n_in,
                              void* d_out, int out_size, void* d_ws, size_t ws_size,
                              hipStream_t stream) {
    const float* x    = (const float*)d_in[0];
    const float* imw  = (const float*)d_in[1];
    const int*   y    = (const int*)d_in[3];
    const int*   alph = (const int*)d_in[4];
    float* out = (float*)d_out;

    char* ws = (char*)d_ws;
    double*       accum   = (double*)ws;
    unsigned int* cnt     = (unsigned int*)(ws + 64);
    float*        invbw   = (float*)(ws + 128);
    float*        sq      = (float*)(ws + 4096);
    float*        wgt     = (float*)(ws + 36864);
    float*        colpart = (float*)(ws + 53248);
    unsigned short* xhi   = (unsigned short*)(ws + 577536);

    k_prep<<<NPREP, 256, 0, stream>>>(x, xhi, sq, colpart);
    k_bw<<<1, 256, 0, stream>>>(sq, colpart, imw, y, alph, wgt, invbw, accum, cnt);
    k_pairs<<<NTILES2, 512, 0, stream>>>(xhi, sq, wgt, invbw, accum, cnt, out);
}